// Round 8
// baseline (635.022 us; speedup 1.0000x reference)
//
#include <hip/hip_runtime.h>
#include <math.h>

#define CCH 64
#define NSP 64
#define TAU 0.25f   // |pivot|^2 threshold for the fast pivot path

// ---------------------------------------------------------------------------
// Kernel 1: circular 3x3 conv, per-sample kernels, + bias, + identity kernel.
// (round-1 version; revisit once logdet stops dominating)
// ---------------------------------------------------------------------------
__global__ __launch_bounds__(256) void conv_kernel(
    const float* __restrict__ x, const float* __restrict__ K,
    const float* __restrict__ bias, float* __restrict__ out) {
  int bid = blockIdx.x;            // 0..255
  int b = bid >> 6, co = bid & 63;
  __shared__ float w[CCH * 9];
  __shared__ float tile[64 * 65];
  int t = threadIdx.x;

  for (int i = t; i < CCH * 9; i += 256) {
    float v = K[(size_t)((b * 64 + co) * 64) * 9 + i];
    if (i == co * 9 + 4) v += 1.0f;   // identity: ci==co, kh=kw=1
    w[i] = v;
  }

  int ty = t >> 2;
  int tx = t & 3;
  int x0 = tx << 4;
  float bval = bias[b * 64 + co];
  float acc[16];
#pragma unroll
  for (int i = 0; i < 16; ++i) acc[i] = bval;

  const float* xb = x + (size_t)(b * 64) * 4096;
  for (int ci = 0; ci < 64; ++ci) {
    __syncthreads();
    const float* xc = xb + (size_t)ci * 4096;
#pragma unroll
    for (int j = 0; j < 16; ++j) {
      int i = t + 256 * j;
      tile[(i >> 6) * 65 + (i & 63)] = xc[i];
    }
    __syncthreads();

    float w0 = w[ci * 9 + 0], w1 = w[ci * 9 + 1], w2 = w[ci * 9 + 2];
    float w3 = w[ci * 9 + 3], w4 = w[ci * 9 + 4], w5 = w[ci * 9 + 5];
    float w6 = w[ci * 9 + 6], w7 = w[ci * 9 + 7], w8 = w[ci * 9 + 8];

    int ym = ((ty - 1) & 63) * 65;
    int yc = ty * 65;
    int yp = ((ty + 1) & 63) * 65;
    float in0[18], in1[18], in2[18];
#pragma unroll
    for (int ix = 0; ix < 18; ++ix) {
      int xx = (x0 + ix - 1) & 63;
      in0[ix] = tile[ym + xx];
      in1[ix] = tile[yc + xx];
      in2[ix] = tile[yp + xx];
    }
#pragma unroll
    for (int px = 0; px < 16; ++px) {
      float a = acc[px];
      a = fmaf(w0, in0[px], a); a = fmaf(w1, in0[px + 1], a); a = fmaf(w2, in0[px + 2], a);
      a = fmaf(w3, in1[px], a); a = fmaf(w4, in1[px + 1], a); a = fmaf(w5, in1[px + 2], a);
      a = fmaf(w6, in2[px], a); a = fmaf(w7, in2[px + 1], a); a = fmaf(w8, in2[px + 2], a);
      acc[px] = a;
    }
  }

  float* op = out + (size_t)(b * 64 + co) * 4096 + ty * 64 + x0;
#pragma unroll
  for (int i = 0; i < 16; i += 4) {
    *(float4*)(op + i) = make_float4(acc[i], acc[i + 1], acc[i + 2], acc[i + 3]);
  }
}

// ---------------------------------------------------------------------------
// Kernel 2: per-frequency 64x64 complex LU -> sum log|pivot|.
// One wave per canonical (b,u,v); lane r owns row r, column-compacted so the
// pivot column is always register index 0. DELTA vs round 7: pivot-row
// broadcast via ds_bpermute_b32 (uniform index p*4) instead of v_readlane.
// bpermute dest is a VGPR -> no VALU->SGPR->VALU hazard NOPs (the measured
// ~40 cyc/element cost common to rounds 6 & 7); DS-pipe ops overlap the
// other resident wave's VALU. Grouped 4-columns-at-a-time so 8 bpermutes
// pipeline under one lgkmcnt wait. No LDS storage, no barriers.
// ---------------------------------------------------------------------------
__device__ __forceinline__ float bperm(int baddr, float x) {
  return __int_as_float(__builtin_amdgcn_ds_bpermute(baddr, __float_as_int(x)));
}

__global__ __launch_bounds__(64, 1) void logdet_kernel(
    const float* __restrict__ K, float* __restrict__ logdet) {
  int u = blockIdx.x >> 6, v = blockIdx.x & 63;
  int b = blockIdx.y;
  int key = blockIdx.x;
  int key2 = (((64 - u) & 63) << 6) | ((64 - v) & 63);
  if (key2 < key) return;                    // conjugate partner, weight 2 below
  float weight = (key2 == key) ? 1.0f : 2.0f;

  int r = threadIdx.x;                       // lane == matrix row

  // twiddles w[kh*3+kw] = e^{-2*pi*i*(u*kh+v*kw)/64} via complex power products
  float Ar[3], Ai[3], Br[3], Bi[3];
  {
    const float k2pi = -6.283185307179586f / 64.0f;
    float su, cu, sv, cv;
    __sincosf(k2pi * (float)u, &su, &cu);
    __sincosf(k2pi * (float)v, &sv, &cv);
    Ar[0] = 1.0f; Ai[0] = 0.0f; Ar[1] = cu; Ai[1] = su;
    Ar[2] = cu * cu - su * su; Ai[2] = 2.0f * cu * su;
    Br[0] = 1.0f; Bi[0] = 0.0f; Br[1] = cv; Bi[1] = sv;
    Br[2] = cv * cv - sv * sv; Bi[2] = 2.0f * cv * sv;
  }
  float wr[9], wi[9];
#pragma unroll
  for (int kh = 0; kh < 3; ++kh)
#pragma unroll
    for (int kw = 0; kw < 3; ++kw) {
      wr[kh * 3 + kw] = Ar[kh] * Br[kw] - Ai[kh] * Bi[kw];
      wi[kh * 3 + kw] = Ar[kh] * Bi[kw] + Ai[kh] * Br[kw];
    }

  // Build row r of Khat with aligned float4 loads (row = 576 floats)
  float ar[65], ai[65];
  const float4* Kp4 = (const float4*)(K + (size_t)(b * 64 + r) * 576);
#pragma unroll
  for (int g = 0; g < 16; ++g) {             // 16 groups x 4 columns
    float f[36];
#pragma unroll
    for (int qq = 0; qq < 9; ++qq) {
      float4 vv = Kp4[g * 9 + qq];
      f[qq * 4 + 0] = vv.x; f[qq * 4 + 1] = vv.y; f[qq * 4 + 2] = vv.z; f[qq * 4 + 3] = vv.w;
    }
#pragma unroll
    for (int cc = 0; cc < 4; ++cc) {
      int c = g * 4 + cc;
      float re = 0.0f, im = 0.0f;
#pragma unroll
      for (int t9 = 0; t9 < 9; ++t9) {
        float kv = f[cc * 9 + t9];
        re = fmaf(kv, wr[t9], re);
        im = fmaf(kv, wi[t9], im);
      }
      if (c == r) { re += wr[4]; im += wi[4]; }  // identity: center-tap delta
      ar[c] = re; ai[c] = im;
    }
  }
  ar[64] = 0.0f; ai[64] = 0.0f;              // pad slot read by chunk 3

  bool active = true;
  float logsum = 0.0f;

  for (int k = 0; k < 63; ++k) {
    float mag = fmaf(ar[0], ar[0], ai[0] * ai[0]);
    bool cand = active && (mag >= TAU);
    unsigned long long candm = __ballot(cand);
    int p;
    if (candm != 0ULL) {
      p = __ffsll(candm) - 1;                // fast path: first big-enough pivot
    } else {                                 // rare: all remaining pivots tiny
      float mm = active ? mag : -1.0f;
#pragma unroll
      for (int off = 32; off > 0; off >>= 1) mm = fmaxf(mm, __shfl_xor(mm, off));
      unsigned long long mx = __ballot(active && (mag == mm));
      if (mx == 0ULL) mx = __ballot(active); // degenerate (NaN) guard
      p = __ffsll(mx) - 1;
    }
    p = __builtin_amdgcn_readfirstlane(p) & 63;  // uniform, always-valid lane
    int baddr = p << 2;                      // bpermute byte index (broadcast)

    if (r == p) {                            // retire pivot lane: log its pivot
      logsum += 0.5f * __logf(mag);
      active = false;
    }

    float pr = bperm(baddr, ar[0]);
    float pi = bperm(baddr, ai[0]);
    float inv = 1.0f / fmaf(pr, pr, pi * pi);
    float fre = (ar[0] * pr + ai[0] * pi) * inv;
    float fim = (ai[0] * pr - ar[0] * pi) * inv;
    fre = active ? fre : 0.0f;               // pivot + retired lanes: shift-only
    fim = active ? fim : 0.0f;

    int rem = 63 - k;                        // remaining columns at indices 1..rem
#pragma unroll
    for (int ch = 0; ch < 4; ++ch) {
      if (ch * 16 < rem) {                   // uniform scalar guard
#pragma unroll
        for (int g4 = 0; g4 < 4; ++g4) {     // 4 columns per group: 8 bpermutes
          int c0 = ch * 16 + g4 * 4 + 1;     // pipeline under one lgkmcnt wait
          float lr0 = bperm(baddr, ar[c0 + 0]);
          float lr1 = bperm(baddr, ar[c0 + 1]);
          float lr2 = bperm(baddr, ar[c0 + 2]);
          float lr3 = bperm(baddr, ar[c0 + 3]);
          float li0 = bperm(baddr, ai[c0 + 0]);
          float li1 = bperm(baddr, ai[c0 + 1]);
          float li2 = bperm(baddr, ai[c0 + 2]);
          float li3 = bperm(baddr, ai[c0 + 3]);
          ar[c0 - 1] = fmaf(fim, li0, fmaf(-fre, lr0, ar[c0 + 0]));
          ai[c0 - 1] = fmaf(-fim, lr0, fmaf(-fre, li0, ai[c0 + 0]));
          ar[c0 + 0] = fmaf(fim, li1, fmaf(-fre, lr1, ar[c0 + 1]));
          ai[c0 + 0] = fmaf(-fim, lr1, fmaf(-fre, li1, ai[c0 + 1]));
          ar[c0 + 1] = fmaf(fim, li2, fmaf(-fre, lr2, ar[c0 + 2]));
          ai[c0 + 1] = fmaf(-fim, lr2, fmaf(-fre, li2, ai[c0 + 2]));
          ar[c0 + 2] = fmaf(fim, li3, fmaf(-fre, lr3, ar[c0 + 3]));
          ai[c0 + 2] = fmaf(-fim, lr3, fmaf(-fre, li3, ai[c0 + 3]));
        }
      }
    }
  }
  if (active) logsum += 0.5f * __logf(fmaf(ar[0], ar[0], ai[0] * ai[0]));

#pragma unroll
  for (int off = 32; off > 0; off >>= 1) logsum += __shfl_xor(logsum, off);
  if (r == 0) atomicAdd(&logdet[b], weight * logsum);
}

// ---------------------------------------------------------------------------
extern "C" void kernel_launch(void* const* d_in, const int* in_sizes, int n_in,
                              void* d_out, int out_size, void* d_ws, size_t ws_size,
                              hipStream_t stream) {
  const float* conv_in = (const float*)d_in[0];   // [4,64,64,64]
  const float* K       = (const float*)d_in[1];   // [4,64,64,3,3]
  const float* bias    = (const float*)d_in[2];   // [4,64,1,1]
  float* out = (float*)d_out;                     // conv_out (1048576) ++ logdet (4)
  float* logdet = out + 1048576;

  hipMemsetAsync(logdet, 0, 4 * sizeof(float), stream);
  conv_kernel<<<dim3(256), dim3(256), 0, stream>>>(conv_in, K, bias, out);
  logdet_kernel<<<dim3(4096, 4), dim3(64), 0, stream>>>(K, logdet);
}

// Round 9
// 504.858 us; speedup vs baseline: 1.2578x; 1.2578x over previous
//
#include <hip/hip_runtime.h>
#include <math.h>

#define CCH 64
#define NSP 64
#define TAU 0.25f   // |pivot|^2 threshold for the fast pivot path

// ---------------------------------------------------------------------------
// Kernel 1: circular 3x3 conv, per-sample kernels, + bias, + identity kernel.
// (round-1 version; revisit once logdet stops dominating)
// ---------------------------------------------------------------------------
__global__ __launch_bounds__(256) void conv_kernel(
    const float* __restrict__ x, const float* __restrict__ K,
    const float* __restrict__ bias, float* __restrict__ out) {
  int bid = blockIdx.x;            // 0..255
  int b = bid >> 6, co = bid & 63;
  __shared__ float w[CCH * 9];
  __shared__ float tile[64 * 65];
  int t = threadIdx.x;

  for (int i = t; i < CCH * 9; i += 256) {
    float v = K[(size_t)((b * 64 + co) * 64) * 9 + i];
    if (i == co * 9 + 4) v += 1.0f;   // identity: ci==co, kh=kw=1
    w[i] = v;
  }

  int ty = t >> 2;
  int tx = t & 3;
  int x0 = tx << 4;
  float bval = bias[b * 64 + co];
  float acc[16];
#pragma unroll
  for (int i = 0; i < 16; ++i) acc[i] = bval;

  const float* xb = x + (size_t)(b * 64) * 4096;
  for (int ci = 0; ci < 64; ++ci) {
    __syncthreads();
    const float* xc = xb + (size_t)ci * 4096;
#pragma unroll
    for (int j = 0; j < 16; ++j) {
      int i = t + 256 * j;
      tile[(i >> 6) * 65 + (i & 63)] = xc[i];
    }
    __syncthreads();

    float w0 = w[ci * 9 + 0], w1 = w[ci * 9 + 1], w2 = w[ci * 9 + 2];
    float w3 = w[ci * 9 + 3], w4 = w[ci * 9 + 4], w5 = w[ci * 9 + 5];
    float w6 = w[ci * 9 + 6], w7 = w[ci * 9 + 7], w8 = w[ci * 9 + 8];

    int ym = ((ty - 1) & 63) * 65;
    int yc = ty * 65;
    int yp = ((ty + 1) & 63) * 65;
    float in0[18], in1[18], in2[18];
#pragma unroll
    for (int ix = 0; ix < 18; ++ix) {
      int xx = (x0 + ix - 1) & 63;
      in0[ix] = tile[ym + xx];
      in1[ix] = tile[yc + xx];
      in2[ix] = tile[yp + xx];
    }
#pragma unroll
    for (int px = 0; px < 16; ++px) {
      float a = acc[px];
      a = fmaf(w0, in0[px], a); a = fmaf(w1, in0[px + 1], a); a = fmaf(w2, in0[px + 2], a);
      a = fmaf(w3, in1[px], a); a = fmaf(w4, in1[px + 1], a); a = fmaf(w5, in1[px + 2], a);
      a = fmaf(w6, in2[px], a); a = fmaf(w7, in2[px + 1], a); a = fmaf(w8, in2[px + 2], a);
      acc[px] = a;
    }
  }

  float* op = out + (size_t)(b * 64 + co) * 4096 + ty * 64 + x0;
#pragma unroll
  for (int i = 0; i < 16; i += 4) {
    *(float4*)(op + i) = make_float4(acc[i], acc[i + 1], acc[i + 2], acc[i + 3]);
  }
}

// ---------------------------------------------------------------------------
// Kernel 2: per-frequency 64x64 complex LU -> sum log|pivot|.
// One wave per canonical (b,u,v); lane r owns row r, column-compacted so the
// pivot column is always register index 0. Pivot row broadcast via
// v_readlane. DELTA vs round 7: BATCHED readlanes -- each 8-column group
// issues its 16 readlanes into a temp array first, then the 32 dependent
// FMAs. First consumer is ~15 instructions downstream of its readlane, so
// the VALU->SGPR->VALU read-after-write wait states (the measured ~40
// cyc/element common to rounds 6 & 7) are hidden. No LDS, no barriers.
// ---------------------------------------------------------------------------
__device__ __forceinline__ float rlane(float x, int lane) {
  return __int_as_float(__builtin_amdgcn_readlane(__float_as_int(x), lane));
}

__global__ __launch_bounds__(64, 1) void logdet_kernel(
    const float* __restrict__ K, float* __restrict__ logdet) {
  int u = blockIdx.x >> 6, v = blockIdx.x & 63;
  int b = blockIdx.y;
  int key = blockIdx.x;
  int key2 = (((64 - u) & 63) << 6) | ((64 - v) & 63);
  if (key2 < key) return;                    // conjugate partner, weight 2 below
  float weight = (key2 == key) ? 1.0f : 2.0f;

  int r = threadIdx.x;                       // lane == matrix row

  // twiddles w[kh*3+kw] = e^{-2*pi*i*(u*kh+v*kw)/64} via complex power products
  float Ar[3], Ai[3], Br[3], Bi[3];
  {
    const float k2pi = -6.283185307179586f / 64.0f;
    float su, cu, sv, cv;
    __sincosf(k2pi * (float)u, &su, &cu);
    __sincosf(k2pi * (float)v, &sv, &cv);
    Ar[0] = 1.0f; Ai[0] = 0.0f; Ar[1] = cu; Ai[1] = su;
    Ar[2] = cu * cu - su * su; Ai[2] = 2.0f * cu * su;
    Br[0] = 1.0f; Bi[0] = 0.0f; Br[1] = cv; Bi[1] = sv;
    Br[2] = cv * cv - sv * sv; Bi[2] = 2.0f * cv * sv;
  }
  float wr[9], wi[9];
#pragma unroll
  for (int kh = 0; kh < 3; ++kh)
#pragma unroll
    for (int kw = 0; kw < 3; ++kw) {
      wr[kh * 3 + kw] = Ar[kh] * Br[kw] - Ai[kh] * Bi[kw];
      wi[kh * 3 + kw] = Ar[kh] * Bi[kw] + Ai[kh] * Br[kw];
    }

  // Build row r of Khat with aligned float4 loads (row = 576 floats)
  float ar[65], ai[65];
  const float4* Kp4 = (const float4*)(K + (size_t)(b * 64 + r) * 576);
#pragma unroll
  for (int g = 0; g < 16; ++g) {             // 16 groups x 4 columns
    float f[36];
#pragma unroll
    for (int qq = 0; qq < 9; ++qq) {
      float4 vv = Kp4[g * 9 + qq];
      f[qq * 4 + 0] = vv.x; f[qq * 4 + 1] = vv.y; f[qq * 4 + 2] = vv.z; f[qq * 4 + 3] = vv.w;
    }
#pragma unroll
    for (int cc = 0; cc < 4; ++cc) {
      int c = g * 4 + cc;
      float re = 0.0f, im = 0.0f;
#pragma unroll
      for (int t9 = 0; t9 < 9; ++t9) {
        float kv = f[cc * 9 + t9];
        re = fmaf(kv, wr[t9], re);
        im = fmaf(kv, wi[t9], im);
      }
      if (c == r) { re += wr[4]; im += wi[4]; }  // identity: center-tap delta
      ar[c] = re; ai[c] = im;
    }
  }
  ar[64] = 0.0f; ai[64] = 0.0f;              // pad slot read by chunk 3

  bool active = true;
  float logsum = 0.0f;

  for (int k = 0; k < 63; ++k) {
    float mag = fmaf(ar[0], ar[0], ai[0] * ai[0]);
    bool cand = active && (mag >= TAU);
    unsigned long long candm = __ballot(cand);
    int p;
    if (candm != 0ULL) {
      p = __ffsll(candm) - 1;                // fast path: first big-enough pivot
    } else {                                 // rare: all remaining pivots tiny
      float mm = active ? mag : -1.0f;
#pragma unroll
      for (int off = 32; off > 0; off >>= 1) mm = fmaxf(mm, __shfl_xor(mm, off));
      unsigned long long mx = __ballot(active && (mag == mm));
      if (mx == 0ULL) mx = __ballot(active); // degenerate (NaN) guard
      p = __ffsll(mx) - 1;
    }
    p = __builtin_amdgcn_readfirstlane(p) & 63;  // uniform, always-valid lane

    if (r == p) {                            // retire pivot lane: log its pivot
      logsum += 0.5f * __logf(mag);
      active = false;
    }

    float pr = rlane(ar[0], p);
    float pi = rlane(ai[0], p);
    float inv = 1.0f / fmaf(pr, pr, pi * pi);
    float fre = (ar[0] * pr + ai[0] * pi) * inv;
    float fim = (ai[0] * pr - ar[0] * pi) * inv;
    fre = active ? fre : 0.0f;               // pivot + retired lanes: shift-only
    fim = active ? fim : 0.0f;

    int rem = 63 - k;                        // remaining columns at indices 1..rem
#pragma unroll
    for (int ch = 0; ch < 4; ++ch) {
      if (ch * 16 < rem) {                   // uniform scalar guard
#pragma unroll
        for (int g8 = 0; g8 < 2; ++g8) {     // 8 columns per batch
          int c0 = ch * 16 + g8 * 8 + 1;
          float lrA[8], liA[8];
          // phase 1: 16 readlanes, no consumers in range -> hazard hidden
#pragma unroll
          for (int e = 0; e < 8; ++e) {
            lrA[e] = rlane(ar[c0 + e], p);
            liA[e] = rlane(ai[c0 + e], p);
          }
          // phase 2: 32 FMAs consuming the batch
#pragma unroll
          for (int e = 0; e < 8; ++e) {
            int c = c0 + e;
            ar[c - 1] = fmaf(fim, liA[e], fmaf(-fre, lrA[e], ar[c]));
            ai[c - 1] = fmaf(-fim, lrA[e], fmaf(-fre, liA[e], ai[c]));
          }
        }
      }
    }
  }
  if (active) logsum += 0.5f * __logf(fmaf(ar[0], ar[0], ai[0] * ai[0]));

#pragma unroll
  for (int off = 32; off > 0; off >>= 1) logsum += __shfl_xor(logsum, off);
  if (r == 0) atomicAdd(&logdet[b], weight * logsum);
}

// ---------------------------------------------------------------------------
extern "C" void kernel_launch(void* const* d_in, const int* in_sizes, int n_in,
                              void* d_out, int out_size, void* d_ws, size_t ws_size,
                              hipStream_t stream) {
  const float* conv_in = (const float*)d_in[0];   // [4,64,64,64]
  const float* K       = (const float*)d_in[1];   // [4,64,64,3,3]
  const float* bias    = (const float*)d_in[2];   // [4,64,1,1]
  float* out = (float*)d_out;                     // conv_out (1048576) ++ logdet (4)
  float* logdet = out + 1048576;

  hipMemsetAsync(logdet, 0, 4 * sizeof(float), stream);
  conv_kernel<<<dim3(256), dim3(256), 0, stream>>>(conv_in, K, bias, out);
  logdet_kernel<<<dim3(4096, 4), dim3(64), 0, stream>>>(K, logdet);
}